// Round 3
// baseline (132.102 us; speedup 1.0000x reference)
//
#include <hip/hip_runtime.h>

#define N_TOTAL 32768
#define D_DIM   512
#define C_DIM   64
#define K_DIM   16
#define M_DIM   128
#define NODES_  15

typedef unsigned short u16;
typedef unsigned int   u32;
typedef unsigned long long u64;
typedef unsigned char  u8;
typedef float  f32x4  __attribute__((ext_vector_type(4)));
typedef short  short8v __attribute__((ext_vector_type(8)));

__device__ __forceinline__ u32 f2bf_bits(float f) {
    u32 u = __float_as_uint(f);
    return (u + 0x7FFFu + ((u >> 16) & 1u)) >> 16;   // RNE
}

__device__ __forceinline__ void gload_lds4(const float* g, float* l) {
    __builtin_amdgcn_global_load_lds(
        (const __attribute__((address_space(1))) void*)g,
        (__attribute__((address_space(3))) void*)l, 4, 0, 0);
}

// ---------------------------------------------------------------------------
// Kernel 1: Lb[m][k] = bf16(L[m][k]), 128x1024, 256 KB (L2-resident).
// ---------------------------------------------------------------------------
__global__ __launch_bounds__(256) void build_lb(
    const float* __restrict__ L, u16* __restrict__ Lb)
{
    int i0 = (blockIdx.x * 256 + threadIdx.x) * 8;   // 64 blocks
    float4 a = *(const float4*)(L + i0);
    float4 b = *(const float4*)(L + i0 + 4);
    u32 w0 = f2bf_bits(a.x) | (f2bf_bits(a.y) << 16);
    u32 w1 = f2bf_bits(a.z) | (f2bf_bits(a.w) << 16);
    u32 w2 = f2bf_bits(b.x) | (f2bf_bits(b.y) << 16);
    u32 w3 = f2bf_bits(b.z) | (f2bf_bits(b.w) << 16);
    *(uint4*)(Lb + i0) = make_uint4(w0, w1, w2, w3);
}

// ---------------------------------------------------------------------------
// Kernel 2: codes. Verified r2 phase-0/1 structure, but stages only the 256
// dims-gathered columns per row (16 KB LDS, phase-1 reads become b128).
// Wave wv owns rows blockIdx.x*16 + 4wv..+3; lane = class.
// Output: cws[class][n] u8 code (2 MB, [64][32768], one u32 store per lane).
// sign(h) descent == argmax leaf; h==0 -> bit 0 == argmax first-max tie rule.
// ---------------------------------------------------------------------------
__global__ __launch_bounds__(256) void codes_kernel(
    const float* __restrict__ I,
    const float* __restrict__ T,
    const int* __restrict__ dims,
    u8* __restrict__ cws)
{
    __shared__ float sIg[16 * 256];         // 16 KB: [row][dim-position j]
    __shared__ float sT[C_DIM * NODES_];    // 3.75 KB

    const int tid  = threadIdx.x;
    const int lane = tid & 63;              // class c in phase 1
    const int wv   = tid >> 6;
    const int rowBase = blockIdx.x * 16 + wv * 4;

    // per-lane dim values for staging positions j = i*64 + lane
    int dlv[4];
    #pragma unroll
    for (int i = 0; i < 4; ++i) dlv[i] = dims[i * 64 + lane];

    // gathered stage: sIg[row][j] = I[row][dims[j]] (dst lane-linear 4 B)
    #pragma unroll
    for (int rr = 0; rr < 4; ++rr) {
        const float* src = I + (size_t)(rowBase + rr) * D_DIM;
        float* dst = sIg + (wv * 4 + rr) * 256;
        #pragma unroll
        for (int i = 0; i < 4; ++i)
            gload_lds4(src + dlv[i], dst + i * 64);
    }

    for (int j = tid; j < C_DIM * NODES_; j += 256) sT[j] = T[j];
    __syncthreads();

    // depth-4 descent; lane c reads its 4 levels contiguously (b128)
    const float* tc = sT + lane * NODES_;
    u32 cp = 0;
    #pragma unroll
    for (int rr = 0; rr < 4; ++rr) {
        const float4 x = *(const float4*)(sIg + (wv * 4 + rr) * 256 + lane * 4);
        int node = 0, k = 0;
        int b0 = (x.x - tc[0] > 0.0f) ? 1 : 0;
        k = b0; node = 1 + b0;
        int b1 = (x.y - tc[node] > 0.0f) ? 1 : 0;
        k = (k << 1) | b1; node = (node << 1) + 1 + b1;
        int b2 = (x.z - tc[node] > 0.0f) ? 1 : 0;
        k = (k << 1) | b2; node = (node << 1) + 1 + b2;
        int b3 = (x.w - tc[node] > 0.0f) ? 1 : 0;
        k = (k << 1) | b3;
        cp |= (u32)k << (4 * rr);
    }

    // pack 4 rows' codes as 4 bytes, one dword store per lane (class-major)
    u32 cw =  (cp & 0xFu)
           | ((cp >> 4)  & 0xFu) << 8
           | ((cp >> 8)  & 0xFu) << 16
           | ((cp >> 12) & 0xFu) << 24;
    *(u32*)(cws + (size_t)lane * N_TOTAL + rowBase) = cw;
}

// ---------------------------------------------------------------------------
// Kernel 3: out = E @ Lb^T via MFMA. 64 rows/block, 4 waves; wave = 4
// row-tiles x 2 col-tiles (acc 8 frags, 32 VGPR). A-frag is a synthesized
// one-hot (64-bit shift from the 4-bit code); B-frag = 16 B of Lb from L2,
// reused across 4 row-tiles. A and B use the same (lane,i)->k map, so any
// hw k-permutation cancels. C/D: col=lane&15, row=(lane>>4)*4+j (m89).
// ---------------------------------------------------------------------------
__global__ __launch_bounds__(256) void gemm_kernel(
    const u16* __restrict__ Lb,
    const u8* __restrict__ cws,
    float* __restrict__ out)
{
    __shared__ u8 sC[C_DIM * 64];           // 4 KB: [class][64 local rows]

    const int tid  = threadIdx.x;
    const int lane = tid & 63;
    const int wv   = tid >> 6;
    const int rowBase = blockIdx.x * 64;

    // stage this block's code slice: 64 classes x 64 rows
    {
        int cls = tid >> 2, off = (tid & 3) * 16;
        *(uint4*)(sC + cls * 64 + off) =
            *(const uint4*)(cws + (size_t)cls * N_TOTAL + rowBase + off);
    }
    __syncthreads();

    const int l15     = lane & 15;
    const int clsLane = (lane >> 5) & 1;        // which class of the k-chunk
    const int kb      = ((lane >> 4) & 1) * 8;  // k-offset within the class

    f32x4 acc[4][2] = {};

    // B base addresses for this wave's two col-tiles
    const u16* lb0 = Lb + (size_t)((wv * 2 + 0) * 16 + l15) * 1024 + ((lane >> 4) * 8);
    const u16* lb1 = Lb + (size_t)((wv * 2 + 1) * 16 + l15) * 1024 + ((lane >> 4) * 8);

    #pragma unroll 4
    for (int ch = 0; ch < 32; ++ch) {
        union { uint4 u; short8v v; } b0, b1;
        b0.u = *(const uint4*)(lb0 + ch * 32);
        b1.u = *(const uint4*)(lb1 + ch * 32);
        const int cls = ch * 2 + clsLane;
        #pragma unroll
        for (int rt = 0; rt < 4; ++rt) {
            u32 cd = sC[cls * 64 + rt * 16 + l15];
            u32 tt = cd - (u32)kb;              // one-hot slot if 0..7
            u64 sv = 0x3F80ull << ((tt & 3) * 16);
            union { u64 d[2]; short8v v; } a;
            a.d[0] = (tt < 4) ? sv : 0ull;
            a.d[1] = (tt >= 4 && tt < 8) ? sv : 0ull;
            acc[rt][0] = __builtin_amdgcn_mfma_f32_16x16x32_bf16(
                             a.v, b0.v, acc[rt][0], 0, 0, 0);
            acc[rt][1] = __builtin_amdgcn_mfma_f32_16x16x32_bf16(
                             a.v, b1.v, acc[rt][1], 0, 0, 0);
        }
    }

    // epilogue: D row = (lane>>4)*4 + j, col = lane&15 (within 16x16 tile)
    #pragma unroll
    for (int rt = 0; rt < 4; ++rt) {
        #pragma unroll
        for (int cj = 0; cj < 2; ++cj) {
            int col = (wv * 2 + cj) * 16 + l15;
            int r0  = rowBase + rt * 16 + ((lane >> 4) << 2);
            float* o = out + (size_t)r0 * M_DIM + col;
            o[0 * M_DIM] = acc[rt][cj][0];
            o[1 * M_DIM] = acc[rt][cj][1];
            o[2 * M_DIM] = acc[rt][cj][2];
            o[3 * M_DIM] = acc[rt][cj][3];
        }
    }
}

extern "C" void kernel_launch(void* const* d_in, const int* in_sizes, int n_in,
                              void* d_out, int out_size, void* d_ws, size_t ws_size,
                              hipStream_t stream) {
    // inputs: I(0) T(1) L(2) S(3) B(4) dims(5) temp(6) — fp32, dims int32
    const float* I    = (const float*)d_in[0];
    const float* T    = (const float*)d_in[1];
    const float* L    = (const float*)d_in[2];
    const int*   dims = (const int*)d_in[5];

    u16* Lb = (u16*)d_ws;                       // 256 KB
    u8*  cw = (u8*)d_ws + (1 << 18);            // 2 MB: [64][32768]

    hipLaunchKernelGGL(build_lb,   dim3(64),   dim3(256), 0, stream, L, Lb);
    hipLaunchKernelGGL(codes_kernel, dim3(N_TOTAL / 16), dim3(256), 0, stream,
                       I, T, dims, cw);
    hipLaunchKernelGGL(gemm_kernel, dim3(N_TOTAL / 64), dim3(256), 0, stream,
                       Lb, cw, (float*)d_out);
}

// Round 4
// 129.828 us; speedup vs baseline: 1.0175x; 1.0175x over previous
//
#include <hip/hip_runtime.h>

#define N_TOTAL 32768
#define D_DIM   512
#define C_DIM   64
#define K_DIM   16
#define M_DIM   128
#define NODES_  15
#define ROWS    16

typedef unsigned short u16;
typedef unsigned int   u32;
typedef unsigned long long u64;
typedef unsigned char  u8;
typedef float  f32x4  __attribute__((ext_vector_type(4)));
typedef short  short8v __attribute__((ext_vector_type(8)));

__device__ __forceinline__ u32 f2bf_bits(float f) {
    u32 u = __float_as_uint(f);
    return (u + 0x7FFFu + ((u >> 16) & 1u)) >> 16;   // RNE
}

// coalesced global -> LDS direct copy, 16 B/lane (wave-uniform LDS base)
__device__ __forceinline__ void gload_lds16(const float* g, float* l) {
    __builtin_amdgcn_global_load_lds(
        (const __attribute__((address_space(1))) void*)g,
        (__attribute__((address_space(3))) void*)l, 16, 0, 0);
}

// ---------------------------------------------------------------------------
// Kernel 1: Lbf = L in MFMA-B-fragment order, bf16.
// Fragment (ct, ch): lane holds B[k][n] for n = ct*16 + (lane&15),
// k = ch*32 + (lane>>4)*8 + i (i=0..7). Layout [ct][ch][lane][8] -> each
// B-load in the gemm is one contiguous 1 KB wave read. 256 KB, L2-resident.
// ---------------------------------------------------------------------------
__global__ __launch_bounds__(256) void build_lbf(
    const float* __restrict__ L, u16* __restrict__ Lbf)
{
    int idx  = blockIdx.x * 256 + threadIdx.x;   // 16384 threads = 64 blocks
    int lane = idx & 63;
    int ch   = (idx >> 6) & 31;
    int ct   = idx >> 11;                        // 0..7
    int m  = ct * 16 + (lane & 15);
    int k0 = ch * 32 + ((lane >> 4) * 8);
    const float* src = L + (size_t)m * 1024 + k0;
    float4 a = *(const float4*)(src);
    float4 b = *(const float4*)(src + 4);
    u32 w0 = f2bf_bits(a.x) | (f2bf_bits(a.y) << 16);
    u32 w1 = f2bf_bits(a.z) | (f2bf_bits(a.w) << 16);
    u32 w2 = f2bf_bits(b.x) | (f2bf_bits(b.y) << 16);
    u32 w3 = f2bf_bits(b.z) | (f2bf_bits(b.w) << 16);
    *(uint4*)(Lbf + (size_t)idx * 8) = make_uint4(w0, w1, w2, w3);
}

// ---------------------------------------------------------------------------
// Kernel 2: codes — EXACT round-2 verified phase 0/1 (coalesced width-16
// global_load_lds staging of full rows + LDS descent), phase 2 replaced by
// one packed u32 store per lane: cws[class][n] u8 (2 MB, class-major).
// sign(h) descent == argmax leaf; h==0 -> bit 0 == argmax first-max tie rule.
// ---------------------------------------------------------------------------
__global__ __launch_bounds__(256) void codes_kernel(
    const float* __restrict__ I,
    const float* __restrict__ T,
    const int* __restrict__ dims,
    u8* __restrict__ cws)
{
    __shared__ float sI[ROWS * D_DIM];      // 32 KB, wave w -> [4w*512 .. )
    __shared__ float sT[C_DIM * NODES_];    // 3.75 KB

    const int tid  = threadIdx.x;
    const int lane = tid & 63;              // class c in descent
    const int wv   = tid >> 6;              // wave 0..3
    const int rowBase = blockIdx.x * ROWS + wv * 4;

    // ---- coalesced stage of this wave's 4 rows (issue first) ----
    {
        const float* src = I + (size_t)rowBase * D_DIM;   // 8 KB contiguous
        float* dst = sI + wv * 4 * D_DIM;
        #pragma unroll
        for (int i = 0; i < 8; ++i)
            gload_lds16(src + i * 256 + lane * 4, dst + i * 256);
    }

    // per-lane dim indices: one coalesced int4 (1 KB, L2-hot)
    const int4 dml = ((const int4*)dims)[lane];

    // stage thresholds while the LDS-stage is in flight
    for (int j = tid; j < C_DIM * NODES_; j += 256) sT[j] = T[j];
    __syncthreads();   // drains vmcnt -> sI and sT both ready

    // ---- depth-4 descent, 4 rows, codes packed into one u32 ----
    const float* tc = sT + lane * NODES_;
    u32 cp = 0;
    #pragma unroll
    for (int rr = 0; rr < 4; ++rr) {
        const float* v = sI + (wv * 4 + rr) * D_DIM;
        float x0 = v[dml.x], x1 = v[dml.y], x2 = v[dml.z], x3 = v[dml.w];
        int node = 0, k = 0;
        int b0 = (x0 - tc[0] > 0.0f) ? 1 : 0;
        k = b0; node = 1 + b0;
        int b1 = (x1 - tc[node] > 0.0f) ? 1 : 0;
        k = (k << 1) | b1; node = (node << 1) + 1 + b1;
        int b2 = (x2 - tc[node] > 0.0f) ? 1 : 0;
        k = (k << 1) | b2; node = (node << 1) + 1 + b2;
        int b3 = (x3 - tc[node] > 0.0f) ? 1 : 0;
        k = (k << 1) | b3;
        cp |= (u32)k << (4 * rr);
    }

    // pack 4 rows' codes as 4 bytes, one dword store per lane (class-major)
    u32 cw =  (cp & 0xFu)
           | ((cp >> 4)  & 0xFu) << 8
           | ((cp >> 8)  & 0xFu) << 16
           | ((cp >> 12) & 0xFu) << 24;
    *(u32*)(cws + (size_t)lane * N_TOTAL + rowBase) = cw;
}

// ---------------------------------------------------------------------------
// Kernel 3: out = E @ Lb^T via MFMA (round-3 verified structure; B now from
// fragment-ordered Lbf -> fully coalesced 1 KB B-loads). 64 rows/block,
// 4 waves; wave = 4 row-tiles x 2 col-tiles. A-frag = synthesized one-hot
// from the 4-bit code. C/D: col=lane&15, row=(lane>>4)*4+j (m89).
// ---------------------------------------------------------------------------
__global__ __launch_bounds__(256) void gemm_kernel(
    const u16* __restrict__ Lbf,
    const u8* __restrict__ cws,
    float* __restrict__ out)
{
    __shared__ u8 sC[C_DIM * 64];           // 4 KB: [class][64 local rows]

    const int tid  = threadIdx.x;
    const int lane = tid & 63;
    const int wv   = tid >> 6;
    const int rowBase = blockIdx.x * 64;

    // stage this block's code slice: 64 classes x 64 rows (coalesced 16 B)
    {
        int cls = tid >> 2, off = (tid & 3) * 16;
        *(uint4*)(sC + cls * 64 + off) =
            *(const uint4*)(cws + (size_t)cls * N_TOTAL + rowBase + off);
    }
    __syncthreads();

    const int l15     = lane & 15;
    const int clsLane = (lane >> 5) & 1;        // which class of the k-chunk
    const int kb      = ((lane >> 4) & 1) * 8;  // k-offset within the class

    f32x4 acc[4][2] = {};

    // fragment-ordered B bases for this wave's two col-tiles
    const u16* lb0 = Lbf + ((size_t)(wv * 2 + 0) * 32 * 64 + lane) * 8;
    const u16* lb1 = Lbf + ((size_t)(wv * 2 + 1) * 32 * 64 + lane) * 8;

    #pragma unroll 4
    for (int ch = 0; ch < 32; ++ch) {
        union { uint4 u; short8v v; } b0, b1;
        b0.u = *(const uint4*)(lb0 + (size_t)ch * 64 * 8);
        b1.u = *(const uint4*)(lb1 + (size_t)ch * 64 * 8);
        const int cls = ch * 2 + clsLane;
        #pragma unroll
        for (int rt = 0; rt < 4; ++rt) {
            u32 cd = sC[cls * 64 + rt * 16 + l15];
            u32 tt = cd - (u32)kb;              // one-hot slot if 0..7
            u64 sv = 0x3F80ull << ((tt & 3) * 16);
            union { u64 d[2]; short8v v; } a;
            a.d[0] = (tt < 4) ? sv : 0ull;
            a.d[1] = (tt >= 4 && tt < 8) ? sv : 0ull;
            acc[rt][0] = __builtin_amdgcn_mfma_f32_16x16x32_bf16(
                             a.v, b0.v, acc[rt][0], 0, 0, 0);
            acc[rt][1] = __builtin_amdgcn_mfma_f32_16x16x32_bf16(
                             a.v, b1.v, acc[rt][1], 0, 0, 0);
        }
    }

    // epilogue: D row = (lane>>4)*4 + j, col = lane&15 (within 16x16 tile)
    #pragma unroll
    for (int rt = 0; rt < 4; ++rt) {
        #pragma unroll
        for (int cj = 0; cj < 2; ++cj) {
            int col = (wv * 2 + cj) * 16 + l15;
            int r0  = rowBase + rt * 16 + ((lane >> 4) << 2);
            float* o = out + (size_t)r0 * M_DIM + col;
            o[0 * M_DIM] = acc[rt][cj][0];
            o[1 * M_DIM] = acc[rt][cj][1];
            o[2 * M_DIM] = acc[rt][cj][2];
            o[3 * M_DIM] = acc[rt][cj][3];
        }
    }
}

extern "C" void kernel_launch(void* const* d_in, const int* in_sizes, int n_in,
                              void* d_out, int out_size, void* d_ws, size_t ws_size,
                              hipStream_t stream) {
    // inputs: I(0) T(1) L(2) S(3) B(4) dims(5) temp(6) — fp32, dims int32
    const float* I    = (const float*)d_in[0];
    const float* T    = (const float*)d_in[1];
    const float* L    = (const float*)d_in[2];
    const int*   dims = (const int*)d_in[5];

    u16* Lbf = (u16*)d_ws;                      // 256 KB, fragment-ordered
    u8*  cw  = (u8*)d_ws + (1 << 18);           // 2 MB: [64][32768]

    hipLaunchKernelGGL(build_lbf, dim3(64), dim3(256), 0, stream, L, Lbf);
    hipLaunchKernelGGL(codes_kernel, dim3(N_TOTAL / ROWS), dim3(256), 0, stream,
                       I, T, dims, cw);
    hipLaunchKernelGGL(gemm_kernel, dim3(N_TOTAL / 64), dim3(256), 0, stream,
                       Lbf, cw, (float*)d_out);
}

// Round 5
// 120.202 us; speedup vs baseline: 1.0990x; 1.0801x over previous
//
#include <hip/hip_runtime.h>

#define N_TOTAL 32768
#define D_DIM   512
#define C_DIM   64
#define K_DIM   16
#define M_DIM   128
#define NODES_  15

typedef unsigned short u16;
typedef unsigned int   u32;
typedef unsigned long long u64;
typedef unsigned char  u8;
typedef float  f32x4   __attribute__((ext_vector_type(4)));
typedef short  short8v __attribute__((ext_vector_type(8)));

__device__ __forceinline__ u32 f2bf_bits(float f) {
    u32 u = __float_as_uint(f);
    return (u + 0x7FFFu + ((u >> 16) & 1u)) >> 16;   // RNE
}

// coalesced global -> LDS direct copy, 16 B/lane (wave-uniform LDS base)
__device__ __forceinline__ void gload_lds16(const float* g, float* l) {
    __builtin_amdgcn_global_load_lds(
        (const __attribute__((address_space(1))) void*)g,
        (__attribute__((address_space(3))) void*)l, 16, 0, 0);
}

// ---------------------------------------------------------------------------
// Kernel 1 (unchanged, r4-verified): Lbf = L in MFMA-B-fragment order, bf16.
// Fragment (ct, ch): lane holds B[k][n], n = ct*16 + (lane&15),
// k = ch*32 + (lane>>4)*8 + i. Layout [ct][ch][lane][8] -> 1 KB coalesced
// wave reads in the gemm. 256 KB, L2-resident.
// ---------------------------------------------------------------------------
__global__ __launch_bounds__(256) void build_lbf(
    const float* __restrict__ L, u16* __restrict__ Lbf)
{
    int idx  = blockIdx.x * 256 + threadIdx.x;   // 16384 threads = 64 blocks
    int lane = idx & 63;
    int ch   = (idx >> 6) & 31;
    int ct   = idx >> 11;                        // 0..7
    int m  = ct * 16 + (lane & 15);
    int k0 = ch * 32 + ((lane >> 4) * 8);
    const float* src = L + (size_t)m * 1024 + k0;
    float4 a = *(const float4*)(src);
    float4 b = *(const float4*)(src + 4);
    u32 w0 = f2bf_bits(a.x) | (f2bf_bits(a.y) << 16);
    u32 w1 = f2bf_bits(a.z) | (f2bf_bits(a.w) << 16);
    u32 w2 = f2bf_bits(b.x) | (f2bf_bits(b.y) << 16);
    u32 w3 = f2bf_bits(b.z) | (f2bf_bits(b.w) << 16);
    *(uint4*)(Lbf + (size_t)idx * 8) = make_uint4(w0, w1, w2, w3);
}

// ---------------------------------------------------------------------------
// Kernel 2 (megakernel): 64 rows/block, 4 waves.
// Codes phase: 4 chunks of 16 rows. Wave wv stages ONLY its own 4 rows per
// chunk (8 x gload_lds16 into its private sI region) -> per-wave vmcnt(0)
// drain, no block barriers in the loop (r2-verified staging + descent).
// Codes written to LDS sC2[cls][l15][rt] (no global round-trip).
// Gemm phase: r4-verified MFMA body; code reads are 1 conflict-free
// ds_read_b32 per chunk. A = synthesized one-hot; B = coalesced Lbf frags.
// C/D: col=lane&15, row=(lane>>4)*4+j (m89). h==0 -> bit 0 == argmax tie.
// ---------------------------------------------------------------------------
__global__ __launch_bounds__(256) void mega_kernel(
    const float* __restrict__ I,
    const float* __restrict__ T,
    const int* __restrict__ dims,
    const u16* __restrict__ Lbf,
    float* __restrict__ out)
{
    __shared__ float sI[16 * D_DIM];        // 32 KB, wave wv -> [4wv*512 ..)
    __shared__ float sT[C_DIM * NODES_];    // 3.75 KB
    __shared__ u8    sC2[C_DIM * 16 * 4];   // 4 KB: [cls][l15][rt]

    const int tid  = threadIdx.x;
    const int lane = tid & 63;              // class c in codes phase
    const int wv   = tid >> 6;
    const int rowBase = blockIdx.x * 64;

    // per-lane dim indices: one coalesced int4 (1 KB, L2-hot)
    const int4 dml = ((const int4*)dims)[lane];

    // issue chunk-0 stage first, fill sT under it
    {
        const float* src = I + (size_t)(rowBase + wv * 4) * D_DIM;
        float* dst = sI + wv * 4 * D_DIM;
        #pragma unroll
        for (int i = 0; i < 8; ++i)
            gload_lds16(src + i * 256 + lane * 4, dst + i * 256);
    }
    for (int j = tid; j < C_DIM * NODES_; j += 256) sT[j] = T[j];
    __syncthreads();    // sT ready; drains chunk-0 vmcnt too

    const float* tc = sT + lane * NODES_;

    #pragma unroll
    for (int ci = 0; ci < 4; ++ci) {
        if (ci) asm volatile("s_waitcnt vmcnt(0)" ::: "memory");  // own stage done
        u32 cp = 0;
        #pragma unroll
        for (int rr = 0; rr < 4; ++rr) {
            const float* v = sI + (wv * 4 + rr) * D_DIM;
            float x0 = v[dml.x], x1 = v[dml.y], x2 = v[dml.z], x3 = v[dml.w];
            int node = 0, k = 0;
            int b0 = (x0 - tc[0] > 0.0f) ? 1 : 0;
            k = b0; node = 1 + b0;
            int b1 = (x1 - tc[node] > 0.0f) ? 1 : 0;
            k = (k << 1) | b1; node = (node << 1) + 1 + b1;
            int b2 = (x2 - tc[node] > 0.0f) ? 1 : 0;
            k = (k << 1) | b2; node = (node << 1) + 1 + b2;
            int b3 = (x3 - tc[node] > 0.0f) ? 1 : 0;
            k = (k << 1) | b3;
            cp |= (u32)k << (4 * rr);
        }
        // scatter 4 nibbles to sC2[lane][wv*4+rr][ci]
        #pragma unroll
        for (int rr = 0; rr < 4; ++rr)
            sC2[lane * 64 + (wv * 4 + rr) * 4 + ci] = (cp >> (4 * rr)) & 15u;
        // issue next chunk's stage (descent data already consumed)
        if (ci < 3) {
            const float* src = I + (size_t)(rowBase + (ci + 1) * 16 + wv * 4) * D_DIM;
            float* dst = sI + wv * 4 * D_DIM;
            #pragma unroll
            for (int i = 0; i < 8; ++i)
                gload_lds16(src + i * 256 + lane * 4, dst + i * 256);
        }
    }
    __syncthreads();    // sC2 complete, all waves

    // ---- gemm phase (r4-verified structure) ----
    const int l15     = lane & 15;
    const int clsLane = (lane >> 5) & 1;        // which class of the k-chunk
    const int kb      = ((lane >> 4) & 1) * 8;  // k-offset within the class

    f32x4 acc[4][2] = {};

    const u16* lb0 = Lbf + ((size_t)(wv * 2 + 0) * 32 * 64 + lane) * 8;
    const u16* lb1 = Lbf + ((size_t)(wv * 2 + 1) * 32 * 64 + lane) * 8;

    #pragma unroll 4
    for (int ch = 0; ch < 32; ++ch) {
        union { uint4 u; short8v v; } b0, b1;
        b0.u = *(const uint4*)(lb0 + (size_t)ch * 64 * 8);
        b1.u = *(const uint4*)(lb1 + (size_t)ch * 64 * 8);
        const int cls = ch * 2 + clsLane;
        // all 4 row-tiles' codes for (cls, l15): one conflict-free b32
        const u32 codes4 = *(const u32*)(sC2 + cls * 64 + l15 * 4);
        #pragma unroll
        for (int rt = 0; rt < 4; ++rt) {
            u32 cd = (codes4 >> (8 * rt)) & 0xFFu;
            u32 tt = cd - (u32)kb;              // one-hot slot if 0..7
            u64 sv = 0x3F80ull << ((tt & 3) * 16);
            union { u64 d[2]; short8v v; } a;
            a.d[0] = (tt < 4) ? sv : 0ull;
            a.d[1] = (tt >= 4 && tt < 8) ? sv : 0ull;
            acc[rt][0] = __builtin_amdgcn_mfma_f32_16x16x32_bf16(
                             a.v, b0.v, acc[rt][0], 0, 0, 0);
            acc[rt][1] = __builtin_amdgcn_mfma_f32_16x16x32_bf16(
                             a.v, b1.v, acc[rt][1], 0, 0, 0);
        }
    }

    // epilogue: D row = (lane>>4)*4 + j, col = lane&15 (within 16x16 tile)
    #pragma unroll
    for (int rt = 0; rt < 4; ++rt) {
        #pragma unroll
        for (int cj = 0; cj < 2; ++cj) {
            int col = (wv * 2 + cj) * 16 + l15;
            int r0  = rowBase + rt * 16 + ((lane >> 4) << 2);
            float* o = out + (size_t)r0 * M_DIM + col;
            o[0 * M_DIM] = acc[rt][cj][0];
            o[1 * M_DIM] = acc[rt][cj][1];
            o[2 * M_DIM] = acc[rt][cj][2];
            o[3 * M_DIM] = acc[rt][cj][3];
        }
    }
}

extern "C" void kernel_launch(void* const* d_in, const int* in_sizes, int n_in,
                              void* d_out, int out_size, void* d_ws, size_t ws_size,
                              hipStream_t stream) {
    // inputs: I(0) T(1) L(2) S(3) B(4) dims(5) temp(6) — fp32, dims int32
    const float* I    = (const float*)d_in[0];
    const float* T    = (const float*)d_in[1];
    const float* L    = (const float*)d_in[2];
    const int*   dims = (const int*)d_in[5];

    u16* Lbf = (u16*)d_ws;                      // 256 KB, fragment-ordered

    hipLaunchKernelGGL(build_lbf, dim3(64), dim3(256), 0, stream, L, Lbf);
    hipLaunchKernelGGL(mega_kernel, dim3(N_TOTAL / 64), dim3(256), 0, stream,
                       I, T, dims, Lbf, (float*)d_out);
}

// Round 6
// 117.697 us; speedup vs baseline: 1.1224x; 1.0213x over previous
//
#include <hip/hip_runtime.h>

#define N_TOTAL 32768
#define D_DIM   512
#define C_DIM   64
#define K_DIM   16
#define M_DIM   128
#define NODES_  15

typedef unsigned short u16;
typedef unsigned int   u32;
typedef unsigned long long u64;
typedef unsigned char  u8;
typedef float  f32x4   __attribute__((ext_vector_type(4)));
typedef short  short8v __attribute__((ext_vector_type(8)));

#define WAIT_VM(N) asm volatile("s_waitcnt vmcnt(" #N ")" ::: "memory")

__device__ __forceinline__ u32 f2bf_bits(float f) {
    u32 u = __float_as_uint(f);
    return (u + 0x7FFFu + ((u >> 16) & 1u)) >> 16;   // RNE
}

// coalesced global -> LDS direct copy, 16 B/lane (wave-uniform LDS base)
__device__ __forceinline__ void gload_lds16(const float* g, float* l) {
    __builtin_amdgcn_global_load_lds(
        (const __attribute__((address_space(1))) void*)g,
        (__attribute__((address_space(3))) void*)l, 16, 0, 0);
}

// ---------------------------------------------------------------------------
// Kernel 1 (unchanged, r4-verified): Lbf = L in MFMA-B-fragment order, bf16.
// Fragment (ct, ch): lane holds B[k][n], n = ct*16 + (lane&15),
// k = ch*32 + (lane>>4)*8 + i. Layout [ct][ch][lane][8] -> 1 KB coalesced
// wave reads in the gemm. 256 KB, L2-resident.
// ---------------------------------------------------------------------------
__global__ __launch_bounds__(256) void build_lbf(
    const float* __restrict__ L, u16* __restrict__ Lbf)
{
    int idx  = blockIdx.x * 256 + threadIdx.x;   // 16384 threads = 64 blocks
    int lane = idx & 63;
    int ch   = (idx >> 6) & 31;
    int ct   = idx >> 11;                        // 0..7
    int m  = ct * 16 + (lane & 15);
    int k0 = ch * 32 + ((lane >> 4) * 8);
    const float* src = L + (size_t)m * 1024 + k0;
    float4 a = *(const float4*)(src);
    float4 b = *(const float4*)(src + 4);
    u32 w0 = f2bf_bits(a.x) | (f2bf_bits(a.y) << 16);
    u32 w1 = f2bf_bits(a.z) | (f2bf_bits(a.w) << 16);
    u32 w2 = f2bf_bits(b.x) | (f2bf_bits(b.y) << 16);
    u32 w3 = f2bf_bits(b.z) | (f2bf_bits(b.w) << 16);
    *(uint4*)(Lbf + (size_t)idx * 8) = make_uint4(w0, w1, w2, w3);
}

// ---------------------------------------------------------------------------
// Kernel 2 (megakernel, r5-verified structure + pipelined staging):
// 64 rows/block, 4 waves. Codes phase: 4 chunks of 16 rows, DOUBLE-BUFFERED
// per-wave sI regions; chunk ci+1's 8 gload_lds16 are issued BEFORE waiting
// on chunk ci (counted vmcnt(8) leaves them in flight through the descent
// window). Codes accumulate in registers; one conflict-free write phase
// (sC2 stride 68 -> bank = lane*17+.. , bijective mod 32).
// Gemm phase: r4/r5-verified MFMA body. A = synthesized one-hot; B =
// coalesced Lbf frags. C/D: col=lane&15, row=(lane>>4)*4+j (m89).
// h==0 -> bit 0 == argmax first-max tie rule.
// ---------------------------------------------------------------------------
__global__ __launch_bounds__(256) void mega_kernel(
    const float* __restrict__ I,
    const float* __restrict__ T,
    const int* __restrict__ dims,
    const u16* __restrict__ Lbf,
    float* __restrict__ out)
{
    __shared__ float sI[2 * 16 * D_DIM];    // 64 KB dbuf, wave wv -> +4wv*512
    __shared__ float sT[C_DIM * NODES_];    // 3.75 KB
    __shared__ u8    sC2[C_DIM * 68];       // 4.25 KB: [cls]{stride 68}[l15*4+rt]

    const int tid  = threadIdx.x;
    const int lane = tid & 63;              // class c in codes phase
    const int wv   = tid >> 6;
    const int rowBase = blockIdx.x * 64;

    // per-lane dim indices: one coalesced int4 (1 KB, L2-hot)
    const int4 dml = ((const int4*)dims)[lane];

    auto issue = [&](int ci, int buf) {
        const float* src = I + (size_t)(rowBase + ci * 16 + wv * 4) * D_DIM;
        float* dst = sI + buf * 16 * D_DIM + wv * 4 * D_DIM;
        #pragma unroll
        for (int i = 0; i < 8; ++i)
            gload_lds16(src + i * 256 + lane * 4, dst + i * 256);
    };

    u32 c4[4] = {0u, 0u, 0u, 0u};   // c4[rr] byte ci = code(chunk ci, row wv*4+rr)
    const float* tc = sT + lane * NODES_;

    auto descend = [&](int buf, int ci) {
        #pragma unroll
        for (int rr = 0; rr < 4; ++rr) {
            const float* v = sI + buf * 16 * D_DIM + (wv * 4 + rr) * D_DIM;
            float x0 = v[dml.x], x1 = v[dml.y], x2 = v[dml.z], x3 = v[dml.w];
            int node = 0, k = 0;
            int b0 = (x0 - tc[0] > 0.0f) ? 1 : 0;
            k = b0; node = 1 + b0;
            int b1 = (x1 - tc[node] > 0.0f) ? 1 : 0;
            k = (k << 1) | b1; node = (node << 1) + 1 + b1;
            int b2 = (x2 - tc[node] > 0.0f) ? 1 : 0;
            k = (k << 1) | b2; node = (node << 1) + 1 + b2;
            int b3 = (x3 - tc[node] > 0.0f) ? 1 : 0;
            k = (k << 1) | b3;
            c4[rr] |= (u32)k << (8 * ci);
        }
    };

    // prologue: chunk 0 staged under the sT fill; barrier drains it
    issue(0, 0);
    for (int j = tid; j < C_DIM * NODES_; j += 256) sT[j] = T[j];
    __syncthreads();                // sT ready, chunk-0 resident
    issue(1, 1);                    // chunk 1 in flight across descent 0

    descend(0, 0);
    issue(2, 0);                    // buf0 reads (chunk 0) already consumed
    WAIT_VM(8);                     // oldest 8 (chunk 1) done, chunk 2 in flight
    descend(1, 1);
    issue(3, 1);
    WAIT_VM(8);                     // chunk 2 done, chunk 3 in flight
    descend(0, 2);
    WAIT_VM(0);                     // chunk 3 done
    descend(1, 3);

    // one conflict-free code-write phase: 4 x ds_write_b32 per lane
    #pragma unroll
    for (int rr = 0; rr < 4; ++rr)
        *(u32*)(sC2 + lane * 68 + (wv * 4 + rr) * 4) = c4[rr];
    __syncthreads();                // sC2 complete, all waves

    // ---- gemm phase (r4/r5-verified structure) ----
    const int l15     = lane & 15;
    const int clsLane = (lane >> 5) & 1;        // which class of the k-chunk
    const int kb      = ((lane >> 4) & 1) * 8;  // k-offset within the class

    f32x4 acc[4][2] = {};

    const u16* lb0 = Lbf + ((size_t)(wv * 2 + 0) * 32 * 64 + lane) * 8;
    const u16* lb1 = Lbf + ((size_t)(wv * 2 + 1) * 32 * 64 + lane) * 8;

    #pragma unroll 4
    for (int ch = 0; ch < 32; ++ch) {
        union { uint4 u; short8v v; } b0, b1;
        b0.u = *(const uint4*)(lb0 + (size_t)ch * 64 * 8);
        b1.u = *(const uint4*)(lb1 + (size_t)ch * 64 * 8);
        const int cls = ch * 2 + clsLane;
        // all 4 row-tiles' codes for (cls, l15): one <=2-way ds_read_b32
        const u32 codes4 = *(const u32*)(sC2 + cls * 68 + l15 * 4);
        #pragma unroll
        for (int rt = 0; rt < 4; ++rt) {
            u32 cd = (codes4 >> (8 * rt)) & 0xFFu;
            u32 tt = cd - (u32)kb;              // one-hot slot if 0..7
            u64 sv = 0x3F80ull << ((tt & 3) * 16);
            union { u64 d[2]; short8v v; } a;
            a.d[0] = (tt < 4) ? sv : 0ull;
            a.d[1] = (tt >= 4 && tt < 8) ? sv : 0ull;
            acc[rt][0] = __builtin_amdgcn_mfma_f32_16x16x32_bf16(
                             a.v, b0.v, acc[rt][0], 0, 0, 0);
            acc[rt][1] = __builtin_amdgcn_mfma_f32_16x16x32_bf16(
                             a.v, b1.v, acc[rt][1], 0, 0, 0);
        }
    }

    // epilogue: D row = (lane>>4)*4 + j, col = lane&15 (within 16x16 tile)
    #pragma unroll
    for (int rt = 0; rt < 4; ++rt) {
        #pragma unroll
        for (int cj = 0; cj < 2; ++cj) {
            int col = (wv * 2 + cj) * 16 + l15;
            int r0  = rowBase + rt * 16 + ((lane >> 4) << 2);
            float* o = out + (size_t)r0 * M_DIM + col;
            o[0 * M_DIM] = acc[rt][cj][0];
            o[1 * M_DIM] = acc[rt][cj][1];
            o[2 * M_DIM] = acc[rt][cj][2];
            o[3 * M_DIM] = acc[rt][cj][3];
        }
    }
}

extern "C" void kernel_launch(void* const* d_in, const int* in_sizes, int n_in,
                              void* d_out, int out_size, void* d_ws, size_t ws_size,
                              hipStream_t stream) {
    // inputs: I(0) T(1) L(2) S(3) B(4) dims(5) temp(6) — fp32, dims int32
    const float* I    = (const float*)d_in[0];
    const float* T    = (const float*)d_in[1];
    const float* L    = (const float*)d_in[2];
    const int*   dims = (const int*)d_in[5];

    u16* Lbf = (u16*)d_ws;                      // 256 KB, fragment-ordered

    hipLaunchKernelGGL(build_lbf, dim3(64), dim3(256), 0, stream, L, Lbf);
    hipLaunchKernelGGL(mega_kernel, dim3(N_TOTAL / 64), dim3(256), 0, stream,
                       I, T, dims, Lbf, (float*)d_out);
}